// Round 4
// baseline (1982.247 us; speedup 1.0000x reference)
//
#include <hip/hip_runtime.h>

#define EPS_DENOM 1e-7f
#define EPS_NORM  1e-5f

static constexpr int D  = 32;    // feature dim
static constexpr int H  = 128;   // hidden dim
static constexpr int BK = 128;   // nodes per bucket  (bucket = node >> 7)
static constexpr int CHUNK = 2048; // edges per binning block

typedef _Float16 f16x8 __attribute__((ext_vector_type(8)));
typedef float    f32x4 __attribute__((ext_vector_type(4)));

// ---------------------------------------------------------------------------
// FCNN via fp16 MFMA (unchanged from R3 — verified). Block = 4 waves = 64 nodes.
// ---------------------------------------------------------------------------
__global__ __launch_bounds__(256) void fcnn_mfma_kernel(
    const float* __restrict__ x,
    const float* __restrict__ W1a, const float* __restrict__ b1a,
    const float* __restrict__ W2a, const float* __restrict__ b2a,
    const float* __restrict__ W1b, const float* __restrict__ b1b,
    const float* __restrict__ W2b, const float* __restrict__ b2b,
    float* __restrict__ h1, _Float16* __restrict__ h2h, int N)
{
    __shared__ _Float16 lds[30208];
    _Float16* xk = lds;

    const int tid = threadIdx.x;
    const int nb0 = blockIdx.x * 64;

    #pragma unroll
    for (int t = 0; t < 8; ++t) {
        int f = t * 256 + tid;
        int node = f >> 5, off = f & 31;
        int gn = nb0 + node;
        float v = (gn < N) ? x[(size_t)gn * 32 + off] : 0.0f;
        xk[node * 40 + off] = (_Float16)v;
    }
    for (int fc = 0; fc < 2; ++fc) {
        const float* W1 = fc ? W1b : W1a;
        const float* W2 = fc ? W2b : W2a;
        _Float16* w1t = lds + 2560 + fc * 5120;    // [h][k], stride 40
        _Float16* w2t = lds + 12800 + fc * 4352;   // [d][k], stride 136
        #pragma unroll
        for (int t = 0; t < 16; ++t) {
            int f = t * 256 + tid;
            w1t[(f & 127) * 40 + (f >> 7)] = (_Float16)W1[f];
        }
        #pragma unroll
        for (int t = 0; t < 16; ++t) {
            int f = t * 256 + tid;
            w2t[(f & 31) * 136 + (f >> 5)] = (_Float16)W2[f];
        }
    }
    __syncthreads();

    const int wid  = tid >> 6;
    const int lane = tid & 63;
    const int m    = lane & 15;
    const int g    = lane >> 4;
    _Float16* t1 = lds + 21504 + wid * 2176;

    f16x8 ax = *(const f16x8*)(xk + (wid * 16 + m) * 40 + g * 8);

    for (int fc = 0; fc < 2; ++fc) {
        const float* b1v = fc ? b1b : b1a;
        const float* b2v = fc ? b2b : b2a;
        const _Float16* w1t = lds + 2560 + fc * 5120;
        const _Float16* w2t = lds + 12800 + fc * 4352;

        for (int hb = 0; hb < 8; ++hb) {
            f16x8 bw = *(const f16x8*)(w1t + (hb * 16 + m) * 40 + g * 8);
            f32x4 c = {0.f, 0.f, 0.f, 0.f};
            c = __builtin_amdgcn_mfma_f32_16x16x32_f16(ax, bw, c, 0, 0, 0);
            float bias = b1v[hb * 16 + m];
            #pragma unroll
            for (int r = 0; r < 4; ++r) {
                float tv = fmaxf(c[r] + bias, 0.0f);
                t1[(g * 4 + r) * 136 + hb * 16 + m] = (_Float16)tv;
            }
        }

        for (int dt = 0; dt < 2; ++dt) {
            f32x4 c2 = {0.f, 0.f, 0.f, 0.f};
            #pragma unroll
            for (int kc = 0; kc < 4; ++kc) {
                f16x8 a2  = *(const f16x8*)(t1 + m * 136 + kc * 32 + g * 8);
                f16x8 b2w = *(const f16x8*)(w2t + (dt * 16 + m) * 136 + kc * 32 + g * 8);
                c2 = __builtin_amdgcn_mfma_f32_16x16x32_f16(a2, b2w, c2, 0, 0, 0);
            }
            float bias = b2v[dt * 16 + m];
            #pragma unroll
            for (int r = 0; r < 4; ++r) {
                int gn = nb0 + wid * 16 + g * 4 + r;
                if (gn < N) {
                    float val = c2[r] + bias;
                    if (fc == 0) h1[(size_t)gn * 32 + dt * 16 + m] = val;
                    else         h2h[(size_t)gn * 32 + dt * 16 + m] = (_Float16)val;
                }
            }
        }
        __syncthreads();
    }
}

// ---------------------------------------------------------------------------
// sigmoid(ef) -> fp16, edge order (coalesced).
// ---------------------------------------------------------------------------
__global__ __launch_bounds__(256) void sprep_kernel(
    const float* __restrict__ ef, _Float16* __restrict__ sgh, int n4)
{
    int i = blockIdx.x * blockDim.x + threadIdx.x;
    if (i >= n4) return;
    float4 v = ((const float4*)ef)[i];
    _Float16 r[4];
    r[0] = (_Float16)(1.0f / (1.0f + __expf(-v.x)));
    r[1] = (_Float16)(1.0f / (1.0f + __expf(-v.y)));
    r[2] = (_Float16)(1.0f / (1.0f + __expf(-v.z)));
    r[3] = (_Float16)(1.0f / (1.0f + __expf(-v.w)));
    ((uint2*)sgh)[i] = *(const uint2*)r;
}

// ---------------------------------------------------------------------------
// Binning: block-local counting sort of 2*CHUNK incidence records by bucket,
// then bucket-grouped coalesced flush to per-bucket global segments.
// Record: .x = (local7 << 21) | eid21 ; .y = (bucket10 << 17) | nbr17
// ---------------------------------------------------------------------------
__global__ __launch_bounds__(256) void bin_kernel(
    const int* __restrict__ ei, int* __restrict__ gcursor,
    uint2* __restrict__ gadj, int E, int CAP)
{
    __shared__ uint2 recs[2 * CHUNK];   // 32 KB
    __shared__ int cnt[1024];
    __shared__ int offs[1024];
    __shared__ int gbase[1024];
    __shared__ int partial[256];

    const int tid  = threadIdx.x;
    const int base = blockIdx.x * CHUNK;
    const int ne   = min(CHUNK, E - base);

    #pragma unroll
    for (int i = 0; i < 4; ++i) cnt[tid * 4 + i] = 0;
    __syncthreads();

    int av[CHUNK / 256], bv[CHUNK / 256];
    #pragma unroll
    for (int j = 0; j < CHUNK / 256; ++j) {
        int r = j * 256 + tid;
        if (r < ne) {
            int e = base + r;
            av[j] = ei[e]; bv[j] = ei[E + e];
            atomicAdd(&cnt[av[j] >> 7], 1);
            atomicAdd(&cnt[bv[j] >> 7], 1);
        } else av[j] = -1;
    }
    __syncthreads();

    // exclusive scan of 1024 counters (4 per thread)
    int c0 = cnt[tid*4], c1 = cnt[tid*4+1], c2 = cnt[tid*4+2], c3 = cnt[tid*4+3];
    int psum = c0 + c1 + c2 + c3;
    partial[tid] = psum;
    __syncthreads();
    for (int off = 1; off < 256; off <<= 1) {
        int t = (tid >= off) ? partial[tid - off] : 0;
        __syncthreads();
        partial[tid] += t;
        __syncthreads();
    }
    int ex = partial[tid] - psum;
    offs[tid*4]   = ex;
    offs[tid*4+1] = ex + c0;
    offs[tid*4+2] = ex + c0 + c1;
    offs[tid*4+3] = ex + c0 + c1 + c2;
    cnt[tid*4]    = ex;
    cnt[tid*4+1]  = ex + c0;
    cnt[tid*4+2]  = ex + c0 + c1;
    cnt[tid*4+3]  = ex + c0 + c1 + c2;
    __syncthreads();

    // scatter records into LDS, grouped by bucket
    #pragma unroll
    for (int j = 0; j < CHUNK / 256; ++j) {
        if (av[j] >= 0) {
            int e = base + j * 256 + tid;
            int a = av[j], b = bv[j];
            int pa = atomicAdd(&cnt[a >> 7], 1);
            recs[pa] = make_uint2(((unsigned)(a & 127) << 21) | (unsigned)e,
                                  ((unsigned)(a >> 7) << 17) | (unsigned)b);
            int pb = atomicAdd(&cnt[b >> 7], 1);
            recs[pb] = make_uint2(((unsigned)(b & 127) << 21) | (unsigned)e,
                                  ((unsigned)(b >> 7) << 17) | (unsigned)a);
        }
    }
    __syncthreads();

    // reserve global space per bucket (one atomic per touched bucket)
    #pragma unroll
    for (int i = 0; i < 4; ++i) {
        int bidx = tid * 4 + i;
        int c = cnt[bidx] - offs[bidx];
        if (c > 0) gbase[bidx] = atomicAdd(&gcursor[bidx], c);
    }
    __syncthreads();

    // flush: consecutive records in a bucket -> consecutive global slots
    int total = 2 * ne;
    for (int i = tid; i < total; i += 256) {
        uint2 r = recs[i];
        int bidx = r.y >> 17;
        int dest = gbase[bidx] + (i - offs[bidx]);
        if (dest < CAP)
            gadj[(size_t)bidx * CAP + dest] = r;
    }
}

// ---------------------------------------------------------------------------
// Aggregation: one block per bucket. S1/S2 for 128 nodes live in 32 KB LDS,
// accumulated with LDS fp32 atomics (addr = local*64 + lane -> conflict-free).
// Fused epilogue: h = h1 + S2/(eps+S1); InstanceNorm; out = x + relu(hn).
// ---------------------------------------------------------------------------
template <bool USE_SG>
__global__ __launch_bounds__(256) void agg_kernel(
    const float* __restrict__ x, const float* __restrict__ ef,
    const _Float16* __restrict__ sgh,
    const float* __restrict__ h1, const _Float16* __restrict__ h2h,
    const int* __restrict__ gcursor, const uint2* __restrict__ gadj,
    float* __restrict__ out, int N, int CAP)
{
    __shared__ float acc[BK * 64];   // [local][0..31]=S1, [32..63]=S2
    const int tid   = threadIdx.x;
    const int bk    = blockIdx.x;
    const int nbase = bk * BK;

    #pragma unroll
    for (int i = 0; i < (BK * 64) / 256; ++i) acc[i * 256 + tid] = 0.0f;
    __syncthreads();

    const int count = gcursor[bk];
    const uint2* badj = gadj + (size_t)bk * CAP;
    const int wid  = tid >> 6;
    const int lane = tid & 63;
    const int dl   = lane & 31;
    const bool hi  = lane >= 32;   // lanes 32-63 accumulate S2, 0-31 S1

    for (int i0 = wid * 8; i0 < count; i0 += 32) {
        uint2 rec[8];
        float val[8];
        int   lc[8];
        #pragma unroll
        for (int u = 0; u < 8; ++u) {
            int i = i0 + u;
            rec[u] = (i < count) ? badj[i] : make_uint2(0xFFFFFFFFu, 0u);
        }
        #pragma unroll
        for (int u = 0; u < 8; ++u) {
            if (rec[u].x != 0xFFFFFFFFu) {
                int eid = rec[u].x & 0x1FFFFF;
                int nbr = rec[u].y & 0x1FFFF;
                lc[u]   = (rec[u].x >> 21) & 127;
                float s;
                if (USE_SG) s = (float)sgh[(size_t)eid * 32 + dl];
                else        s = 1.0f / (1.0f + __expf(-ef[(size_t)eid * 32 + dl]));
                float hh = (float)h2h[(size_t)nbr * 32 + dl];
                val[u] = hi ? s * hh : s;
            }
        }
        #pragma unroll
        for (int u = 0; u < 8; ++u) {
            if (rec[u].x != 0xFFFFFFFFu)
                atomicAdd(&acc[lc[u] * 64 + lane], val[u]);
        }
    }
    __syncthreads();

    const int g = tid >> 5;   // 0..7
    const int d = tid & 31;
    for (int it = 0; it < BK / 8; ++it) {
        int nl = it * 8 + g;
        int gn = nbase + nl;
        if (gn < N) {
            float S1 = acc[nl * 64 + d];
            float S2 = acc[nl * 64 + 32 + d];
            float h  = h1[(size_t)gn * 32 + d] + S2 / (EPS_DENOM + S1);
            float sum = h, sq = h * h;
            #pragma unroll
            for (int off = 16; off > 0; off >>= 1) {
                sum += __shfl_xor(sum, off, 32);
                sq  += __shfl_xor(sq,  off, 32);
            }
            float mu  = sum * (1.0f / 32.0f);
            float var = fmaxf(sq * (1.0f / 32.0f) - mu * mu, 0.0f);
            float hn  = (h - mu) * rsqrtf(var + EPS_NORM);
            out[(size_t)gn * 32 + d] = x[(size_t)gn * 32 + d] + fmaxf(hn, 0.0f);
        }
    }
}

// ---------------------------------------------------------------------------
extern "C" void kernel_launch(void* const* d_in, const int* in_sizes, int n_in,
                              void* d_out, int out_size, void* d_ws, size_t ws_size,
                              hipStream_t stream)
{
    const float* x   = (const float*)d_in[0];
    const float* ef  = (const float*)d_in[1];
    const float* W1a = (const float*)d_in[2];
    const float* b1a = (const float*)d_in[3];
    const float* W2a = (const float*)d_in[4];
    const float* b2a = (const float*)d_in[5];
    const float* W1b = (const float*)d_in[6];
    const float* b1b = (const float*)d_in[7];
    const float* W2b = (const float*)d_in[8];
    const float* b2b = (const float*)d_in[9];
    const int*   ei  = (const int*)d_in[10];
    float* out = (float*)d_out;

    const int N  = in_sizes[0] / D;
    const int E  = in_sizes[1] / D;
    const int NB = (N + BK - 1) / BK;          // buckets (<=1024)
    int CAP = (2 * E) / NB;                    // mean records per bucket
    CAP = CAP + CAP / 2;                       // +50% slack (>>16 sigma)
    CAP = (CAP + 255) & ~255;

    // workspace layout
    char* p = (char*)d_ws;
    float*    h1      = (float*)p;    p += (size_t)N * 32 * 4;
    _Float16* h2h     = (_Float16*)p; p += (size_t)N * 32 * 2;
    int*      gcursor = (int*)p;      p += 1024 * 4;
    uint2*    gadj    = (uint2*)p;    p += (size_t)NB * CAP * 8;
    _Float16* sgh     = (_Float16*)p;
    const bool use_sg = ((size_t)(p - (char*)d_ws) + (size_t)E * 64) <= ws_size;

    hipMemsetAsync(gcursor, 0, 1024 * 4, stream);

    fcnn_mfma_kernel<<<(N + 63) / 64, 256, 0, stream>>>(
        x, W1a, b1a, W2a, b2a, W1b, b1b, W2b, b2b, h1, h2h, N);

    if (use_sg) {
        int n4 = E * 8;
        sprep_kernel<<<(n4 + 255) / 256, 256, 0, stream>>>(ef, sgh, n4);
    }

    bin_kernel<<<(E + CHUNK - 1) / CHUNK, 256, 0, stream>>>(ei, gcursor, gadj, E, CAP);

    if (use_sg)
        agg_kernel<true><<<NB, 256, 0, stream>>>(
            x, ef, sgh, h1, h2h, gcursor, gadj, out, N, CAP);
    else
        agg_kernel<false><<<NB, 256, 0, stream>>>(
            x, ef, sgh, h1, h2h, gcursor, gadj, out, N, CAP);
}

// Round 5
// 555.624 us; speedup vs baseline: 3.5676x; 3.5676x over previous
//
#include <hip/hip_runtime.h>

#define EPS_DENOM 1e-7f
#define EPS_NORM  1e-5f

static constexpr int D  = 32;     // feature dim
static constexpr int H  = 128;    // hidden dim
static constexpr int BK = 128;    // nodes per bucket (bucket = node >> 7)
static constexpr int CHUNK = 3072;    // edges per bin1 block (6144 records, 48 KB LDS)
static constexpr int CAPMAX = 6144;   // max records per bucket (bin2 LDS bound)

typedef _Float16 f16x8 __attribute__((ext_vector_type(8)));
typedef float    f32x4 __attribute__((ext_vector_type(4)));

// ---------------------------------------------------------------------------
// FCNN via fp16 MFMA (unchanged since R3 — verified). Block = 4 waves = 64 nodes.
// ---------------------------------------------------------------------------
__global__ __launch_bounds__(256) void fcnn_mfma_kernel(
    const float* __restrict__ x,
    const float* __restrict__ W1a, const float* __restrict__ b1a,
    const float* __restrict__ W2a, const float* __restrict__ b2a,
    const float* __restrict__ W1b, const float* __restrict__ b1b,
    const float* __restrict__ W2b, const float* __restrict__ b2b,
    float* __restrict__ h1, _Float16* __restrict__ h2h, int N)
{
    __shared__ _Float16 lds[30208];
    _Float16* xk = lds;

    const int tid = threadIdx.x;
    const int nb0 = blockIdx.x * 64;

    #pragma unroll
    for (int t = 0; t < 8; ++t) {
        int f = t * 256 + tid;
        int node = f >> 5, off = f & 31;
        int gn = nb0 + node;
        float v = (gn < N) ? x[(size_t)gn * 32 + off] : 0.0f;
        xk[node * 40 + off] = (_Float16)v;
    }
    for (int fc = 0; fc < 2; ++fc) {
        const float* W1 = fc ? W1b : W1a;
        const float* W2 = fc ? W2b : W2a;
        _Float16* w1t = lds + 2560 + fc * 5120;    // [h][k], stride 40
        _Float16* w2t = lds + 12800 + fc * 4352;   // [d][k], stride 136
        #pragma unroll
        for (int t = 0; t < 16; ++t) {
            int f = t * 256 + tid;
            w1t[(f & 127) * 40 + (f >> 7)] = (_Float16)W1[f];
        }
        #pragma unroll
        for (int t = 0; t < 16; ++t) {
            int f = t * 256 + tid;
            w2t[(f & 31) * 136 + (f >> 5)] = (_Float16)W2[f];
        }
    }
    __syncthreads();

    const int wid  = tid >> 6;
    const int lane = tid & 63;
    const int m    = lane & 15;
    const int g    = lane >> 4;
    _Float16* t1 = lds + 21504 + wid * 2176;

    f16x8 ax = *(const f16x8*)(xk + (wid * 16 + m) * 40 + g * 8);

    for (int fc = 0; fc < 2; ++fc) {
        const float* b1v = fc ? b1b : b1a;
        const float* b2v = fc ? b2b : b2a;
        const _Float16* w1t = lds + 2560 + fc * 5120;
        const _Float16* w2t = lds + 12800 + fc * 4352;

        for (int hb = 0; hb < 8; ++hb) {
            f16x8 bw = *(const f16x8*)(w1t + (hb * 16 + m) * 40 + g * 8);
            f32x4 c = {0.f, 0.f, 0.f, 0.f};
            c = __builtin_amdgcn_mfma_f32_16x16x32_f16(ax, bw, c, 0, 0, 0);
            float bias = b1v[hb * 16 + m];
            #pragma unroll
            for (int r = 0; r < 4; ++r) {
                float tv = fmaxf(c[r] + bias, 0.0f);
                t1[(g * 4 + r) * 136 + hb * 16 + m] = (_Float16)tv;
            }
        }

        for (int dt = 0; dt < 2; ++dt) {
            f32x4 c2 = {0.f, 0.f, 0.f, 0.f};
            #pragma unroll
            for (int kc = 0; kc < 4; ++kc) {
                f16x8 a2  = *(const f16x8*)(t1 + m * 136 + kc * 32 + g * 8);
                f16x8 b2w = *(const f16x8*)(w2t + (dt * 16 + m) * 136 + kc * 32 + g * 8);
                c2 = __builtin_amdgcn_mfma_f32_16x16x32_f16(a2, b2w, c2, 0, 0, 0);
            }
            float bias = b2v[dt * 16 + m];
            #pragma unroll
            for (int r = 0; r < 4; ++r) {
                int gn = nb0 + wid * 16 + g * 4 + r;
                if (gn < N) {
                    float val = c2[r] + bias;
                    if (fc == 0) h1[(size_t)gn * 32 + dt * 16 + m] = val;
                    else         h2h[(size_t)gn * 32 + dt * 16 + m] = (_Float16)val;
                }
            }
        }
        __syncthreads();
    }
}

// ---------------------------------------------------------------------------
// sigmoid(ef) -> fp16, edge order (coalesced).
// ---------------------------------------------------------------------------
__global__ __launch_bounds__(256) void sprep_kernel(
    const float* __restrict__ ef, _Float16* __restrict__ sgh, int n4)
{
    int i = blockIdx.x * blockDim.x + threadIdx.x;
    if (i >= n4) return;
    float4 v = ((const float4*)ef)[i];
    _Float16 r[4];
    r[0] = (_Float16)(1.0f / (1.0f + __expf(-v.x)));
    r[1] = (_Float16)(1.0f / (1.0f + __expf(-v.y)));
    r[2] = (_Float16)(1.0f / (1.0f + __expf(-v.z)));
    r[3] = (_Float16)(1.0f / (1.0f + __expf(-v.w)));
    ((uint2*)sgh)[i] = *(const uint2*)r;
}

// ---------------------------------------------------------------------------
// bin1: block-local counting sort of 2*CHUNK incidence records by bucket,
// bucket-grouped coalesced flush to per-bucket global segments (runs ~7.9 rec).
// Record: .x = (local7 << 21) | eid21 ; .y = (bucket10 << 17) | nbr17
// ---------------------------------------------------------------------------
__global__ __launch_bounds__(256) void bin1_kernel(
    const int* __restrict__ ei, int* __restrict__ gcursor,
    uint2* __restrict__ gadj, int E, int CAP)
{
    __shared__ uint2 recs[2 * CHUNK];   // 48 KB
    __shared__ int cnt[1024];
    __shared__ int offs[1024];
    __shared__ int gbase[1024];
    __shared__ int partial[256];

    const int tid  = threadIdx.x;
    const int base = blockIdx.x * CHUNK;
    const int ne   = min(CHUNK, E - base);

    #pragma unroll
    for (int i = 0; i < 4; ++i) cnt[tid * 4 + i] = 0;
    __syncthreads();

    int av[CHUNK / 256], bv[CHUNK / 256];
    #pragma unroll
    for (int j = 0; j < CHUNK / 256; ++j) {
        int r = j * 256 + tid;
        if (r < ne) {
            int e = base + r;
            av[j] = ei[e]; bv[j] = ei[E + e];
            atomicAdd(&cnt[av[j] >> 7], 1);
            atomicAdd(&cnt[bv[j] >> 7], 1);
        } else av[j] = -1;
    }
    __syncthreads();

    // exclusive scan of 1024 counters (4 per thread)
    int c0 = cnt[tid*4], c1 = cnt[tid*4+1], c2 = cnt[tid*4+2], c3 = cnt[tid*4+3];
    int psum = c0 + c1 + c2 + c3;
    partial[tid] = psum;
    __syncthreads();
    for (int off = 1; off < 256; off <<= 1) {
        int t = (tid >= off) ? partial[tid - off] : 0;
        __syncthreads();
        partial[tid] += t;
        __syncthreads();
    }
    int ex = partial[tid] - psum;
    offs[tid*4]   = ex;
    offs[tid*4+1] = ex + c0;
    offs[tid*4+2] = ex + c0 + c1;
    offs[tid*4+3] = ex + c0 + c1 + c2;
    cnt[tid*4]    = ex;
    cnt[tid*4+1]  = ex + c0;
    cnt[tid*4+2]  = ex + c0 + c1;
    cnt[tid*4+3]  = ex + c0 + c1 + c2;
    __syncthreads();

    // scatter records into LDS, grouped by bucket
    #pragma unroll
    for (int j = 0; j < CHUNK / 256; ++j) {
        if (av[j] >= 0) {
            int e = base + j * 256 + tid;
            int a = av[j], b = bv[j];
            int pa = atomicAdd(&cnt[a >> 7], 1);
            recs[pa] = make_uint2(((unsigned)(a & 127) << 21) | (unsigned)e,
                                  ((unsigned)(a >> 7) << 17) | (unsigned)b);
            int pb = atomicAdd(&cnt[b >> 7], 1);
            recs[pb] = make_uint2(((unsigned)(b & 127) << 21) | (unsigned)e,
                                  ((unsigned)(b >> 7) << 17) | (unsigned)a);
        }
    }
    __syncthreads();

    // reserve global space per bucket
    #pragma unroll
    for (int i = 0; i < 4; ++i) {
        int bidx = tid * 4 + i;
        int c = cnt[bidx] - offs[bidx];
        if (c > 0) gbase[bidx] = atomicAdd(&gcursor[bidx], c);
    }
    __syncthreads();

    // flush: consecutive records in a bucket -> consecutive global slots
    int total = 2 * ne;
    for (int i = tid; i < total; i += 256) {
        uint2 r = recs[i];
        int bidx = r.y >> 17;
        int dest = gbase[bidx] + (i - offs[bidx]);
        if (dest < CAP)
            gadj[(size_t)bidx * CAP + dest] = r;
    }
}

// ---------------------------------------------------------------------------
// bin2: per-bucket counting sort -> CSR. One block per bucket. Records staged
// in LDS; sorted scatter goes back to the same (L2-resident) global segment
// as plain {eid, nbr}. Emits gstart[n], gdeg[n].
// ---------------------------------------------------------------------------
__global__ __launch_bounds__(256) void bin2_kernel(
    const int* __restrict__ gcursor, uint2* __restrict__ gadj,
    int* __restrict__ gstart, int* __restrict__ gdeg,
    int N, int CAP)
{
    __shared__ uint2 recs[CAPMAX];   // 48 KB
    __shared__ int cnt[BK];
    __shared__ int sc[BK];
    __shared__ int lcur[BK];

    const int tid = threadIdx.x;
    const int bk  = blockIdx.x;
    const int count = min(gcursor[bk], CAP);
    uint2* seg = gadj + (size_t)bk * CAP;

    if (tid < BK) cnt[tid] = 0;
    for (int i = tid; i < count; i += 256) recs[i] = seg[i];
    __syncthreads();

    for (int i = tid; i < count; i += 256)
        atomicAdd(&cnt[(recs[i].x >> 21) & 127], 1);
    __syncthreads();

    // inclusive scan over 128 counters (Hillis-Steele, barriers uniform)
    int v = (tid < BK) ? cnt[tid] : 0;
    if (tid < BK) sc[tid] = v;
    __syncthreads();
    for (int off = 1; off < BK; off <<= 1) {
        int t = (tid < BK && tid >= off) ? sc[tid - off] : 0;
        __syncthreads();
        if (tid < BK) sc[tid] += t;
        __syncthreads();
    }
    if (tid < BK) {
        int excl = sc[tid] - v;
        lcur[tid] = excl;
        int gn = bk * BK + tid;
        if (gn < N) {
            gstart[gn] = bk * CAP + excl;
            gdeg[gn]   = v;
        }
    }
    __syncthreads();

    for (int i = tid; i < count; i += 256) {
        uint2 r = recs[i];
        int l = (r.x >> 21) & 127;
        int pos = atomicAdd(&lcur[l], 1);
        seg[pos] = make_uint2(r.x & 0x1FFFFFu, r.y & 0x1FFFFu);  // {eid, nbr}
    }
}

// ---------------------------------------------------------------------------
// Gather + finalize. 32 lanes per node (2 nodes/wave, ~50k waves for TLP).
// 4-edge manual unroll -> 8 random 64B fp16 row loads in flight per group.
// ---------------------------------------------------------------------------
template <bool USE_SG>
__global__ __launch_bounds__(256) void gather_kernel(
    const float* __restrict__ x,  const _Float16* __restrict__ sgh,
    const float* __restrict__ ef, const float* __restrict__ h1,
    const _Float16* __restrict__ h2h,
    const int* __restrict__ gstart, const int* __restrict__ gdeg,
    const uint2* __restrict__ adj2,
    float* __restrict__ out, int N)
{
    int t = blockIdx.x * blockDim.x + threadIdx.x;
    int n = t >> 5;
    int d = t & 31;
    if (n >= N) return;

    int start = gstart[n];
    int end   = start + gdeg[n];

    float s_sum = 0.0f, sh_sum = 0.0f;
    int k = start;
    for (; k + 4 <= end; k += 4) {
        uint2 r0 = adj2[k+0], r1 = adj2[k+1], r2 = adj2[k+2], r3 = adj2[k+3];
        float s0, s1, s2, s3;
        if (USE_SG) {
            s0 = (float)sgh[(size_t)r0.x * 32 + d];
            s1 = (float)sgh[(size_t)r1.x * 32 + d];
            s2 = (float)sgh[(size_t)r2.x * 32 + d];
            s3 = (float)sgh[(size_t)r3.x * 32 + d];
        } else {
            s0 = 1.0f / (1.0f + __expf(-ef[(size_t)r0.x * 32 + d]));
            s1 = 1.0f / (1.0f + __expf(-ef[(size_t)r1.x * 32 + d]));
            s2 = 1.0f / (1.0f + __expf(-ef[(size_t)r2.x * 32 + d]));
            s3 = 1.0f / (1.0f + __expf(-ef[(size_t)r3.x * 32 + d]));
        }
        float h0 = (float)h2h[(size_t)r0.y * 32 + d];
        float h1v = (float)h2h[(size_t)r1.y * 32 + d];
        float h2v = (float)h2h[(size_t)r2.y * 32 + d];
        float h3 = (float)h2h[(size_t)r3.y * 32 + d];
        s_sum += (s0 + s1) + (s2 + s3);
        sh_sum = fmaf(s0, h0, sh_sum);
        sh_sum = fmaf(s1, h1v, sh_sum);
        sh_sum = fmaf(s2, h2v, sh_sum);
        sh_sum = fmaf(s3, h3, sh_sum);
    }
    for (; k < end; ++k) {
        uint2 r = adj2[k];
        float s;
        if (USE_SG) s = (float)sgh[(size_t)r.x * 32 + d];
        else        s = 1.0f / (1.0f + __expf(-ef[(size_t)r.x * 32 + d]));
        float hh = (float)h2h[(size_t)r.y * 32 + d];
        s_sum += s;
        sh_sum = fmaf(s, hh, sh_sum);
    }

    size_t idx = (size_t)n * 32 + d;
    float h = h1[idx] + sh_sum / (EPS_DENOM + s_sum);

    float sum = h, sq = h * h;
    #pragma unroll
    for (int off = 16; off > 0; off >>= 1) {
        sum += __shfl_xor(sum, off, 32);
        sq  += __shfl_xor(sq,  off, 32);
    }
    float mu  = sum * (1.0f / 32.0f);
    float var = fmaxf(sq * (1.0f / 32.0f) - mu * mu, 0.0f);
    float hn  = (h - mu) * rsqrtf(var + EPS_NORM);

    out[idx] = x[idx] + fmaxf(hn, 0.0f);
}

// ---------------------------------------------------------------------------
extern "C" void kernel_launch(void* const* d_in, const int* in_sizes, int n_in,
                              void* d_out, int out_size, void* d_ws, size_t ws_size,
                              hipStream_t stream)
{
    const float* x   = (const float*)d_in[0];
    const float* ef  = (const float*)d_in[1];
    const float* W1a = (const float*)d_in[2];
    const float* b1a = (const float*)d_in[3];
    const float* W2a = (const float*)d_in[4];
    const float* b2a = (const float*)d_in[5];
    const float* W1b = (const float*)d_in[6];
    const float* b1b = (const float*)d_in[7];
    const float* W2b = (const float*)d_in[8];
    const float* b2b = (const float*)d_in[9];
    const int*   ei  = (const int*)d_in[10];
    float* out = (float*)d_out;

    const int N  = in_sizes[0] / D;
    const int E  = in_sizes[1] / D;
    const int NB = (N + BK - 1) / BK;          // buckets (782 for N=100k)
    int CAP = (2 * E) / NB;                    // mean records per bucket
    CAP = CAP + CAP / 2;                       // +50% slack (>>16 sigma)
    CAP = (CAP + 255) & ~255;
    if (CAP > CAPMAX) CAP = CAPMAX;

    // workspace layout
    char* p = (char*)d_ws;
    float*    h1      = (float*)p;    p += (size_t)N * 32 * 4;
    _Float16* h2h     = (_Float16*)p; p += (size_t)N * 32 * 2;
    int*      gcursor = (int*)p;      p += 1024 * 4;
    int*      gstart  = (int*)p;      p += (size_t)N * 4;
    int*      gdeg    = (int*)p;      p += (size_t)N * 4;
    uint2*    gadj    = (uint2*)p;    p += (size_t)NB * CAP * 8;
    _Float16* sgh     = (_Float16*)p;
    const bool use_sg = ((size_t)(p - (char*)d_ws) + (size_t)E * 64) <= ws_size;

    hipMemsetAsync(gcursor, 0, 1024 * 4, stream);

    fcnn_mfma_kernel<<<(N + 63) / 64, 256, 0, stream>>>(
        x, W1a, b1a, W2a, b2a, W1b, b1b, W2b, b2b, h1, h2h, N);

    if (use_sg) {
        int n4 = E * 8;
        sprep_kernel<<<(n4 + 255) / 256, 256, 0, stream>>>(ef, sgh, n4);
    }

    bin1_kernel<<<(E + CHUNK - 1) / CHUNK, 256, 0, stream>>>(ei, gcursor, gadj, E, CAP);
    bin2_kernel<<<NB, 256, 0, stream>>>(gcursor, gadj, gstart, gdeg, N, CAP);

    int gthreads = N * 32;
    if (use_sg)
        gather_kernel<true><<<(gthreads + 255) / 256, 256, 0, stream>>>(
            x, sgh, ef, h1, h2h, gstart, gdeg, gadj, out, N);
    else
        gather_kernel<false><<<(gthreads + 255) / 256, 256, 0, stream>>>(
            x, sgh, ef, h1, h2h, gstart, gdeg, gadj, out, N);
}